// Round 5
// baseline (505.500 us; speedup 1.0000x reference)
//
#include <hip/hip_runtime.h>
#include <math.h>

#define BB 8
#define CC 512
#define KK 19
#define HWHW 16384
#define INV_HW (1.0f/16384.0f)

typedef __attribute__((ext_vector_type(8))) short bf16x8;
typedef __attribute__((ext_vector_type(4))) short s16x4;
typedef __attribute__((ext_vector_type(4))) float f32x4;

__device__ __forceinline__ short f2bf(float f) {
    unsigned int u = __float_as_uint(f);
    u = (u + 0x7fffu + ((u >> 16) & 1u)) >> 16;
    return (short)u;
}

// ============ k_s12: fused mask-GEMM + sigmoid + class_feat partial =========
// 512 blocks = (b=8) x (p-slice s of 64, 256 px). 256 thr (4 waves).
// Phase A: pre_mask[20][256] = Wm @ x ; A=Wm in LDS, B-frags DIRECT from
//   global (4x64B segments/instr, no transpose, no barriers in K-loop).
// Sigmoid in D-regs -> mask tile in LDS (A-layout).
// Phase B: cf_part[s][b][k][c] = mask @ x^T over this p-slice; B-frags direct
//   from global, p-contiguous float4 (L2/L3 hits - tile was just streamed).
__global__ __launch_bounds__(256) void k_s12(const float* __restrict__ x,
                                             const float* __restrict__ Wm,
                                             const float* __restrict__ bm,
                                             float* __restrict__ cf_part) {
    __shared__ short wm[20][520];   // rows pad to 520 shorts = 1040 B == 4 banks rot
    __shared__ short ml[20][264];   // 264 shorts = 528 B == 4 banks rot, 16B aligned
    const int tid = threadIdx.x;
    const int b = blockIdx.x >> 6;
    const int s = blockIdx.x & 63;
    const int p0 = s << 8;
    const float* xb = x + (size_t)b * CC * HWHW;

    for (int u = tid; u < 20 * 128; u += 256) {
        const int k = u >> 7;
        const int c4 = (u & 127) << 2;
        float4 w = {0.f, 0.f, 0.f, 0.f};
        if (k < KK) w = *(const float4*)(Wm + k * CC + c4);
        s16x4 v = { f2bf(w.x), f2bf(w.y), f2bf(w.z), f2bf(w.w) };
        *(s16x4*)&wm[k][c4] = v;
    }
    if (tid < 66) { s16x4 z = {0, 0, 0, 0}; *(s16x4*)&ml[19][tid << 2] = z; }
    __syncthreads();

    const int wv = tid >> 6, ln = tid & 63;
    const int lm = ln & 15, q = ln >> 4;
    const int m1 = (lm < 3) ? (16 + lm) : 19;
    const int pw = p0 + (wv << 6);

    const f32x4 zz = {0.f, 0.f, 0.f, 0.f};
    f32x4 accA[2][4];
#pragma unroll
    for (int i = 0; i < 4; ++i) { accA[0][i] = zz; accA[1][i] = zz; }

    // ---- phase A: K = 512 c, 16 steps of 32 ----
    for (int cs = 0; cs < 16; ++cs) {
        const int cbase = (cs << 5) + (q << 3);
        bf16x8 a0 = *(const bf16x8*)&wm[lm][cbase];
        bf16x8 a1 = *(const bf16x8*)&wm[m1][cbase];
        const float* col = xb + (size_t)cbase * HWHW;
#pragma unroll
        for (int nt = 0; nt < 4; ++nt) {
            const int p = pw + (nt << 4) + lm;
            bf16x8 bv;
#pragma unroll
            for (int j = 0; j < 8; ++j)
                bv[j] = f2bf(col[(size_t)j * HWHW + p]);
            accA[0][nt] = __builtin_amdgcn_mfma_f32_16x16x32_bf16(a0, bv, accA[0][nt], 0, 0, 0);
            accA[1][nt] = __builtin_amdgcn_mfma_f32_16x16x32_bf16(a1, bv, accA[1][nt], 0, 0, 0);
        }
    }

    // ---- sigmoid -> mask tile in LDS (A-layout [k][p]) ----
#pragma unroll
    for (int mt = 0; mt < 2; ++mt)
#pragma unroll
        for (int r = 0; r < 4; ++r) {
            const int k = (mt << 4) + (q << 2) + r;
            if (k < KK) {
                const float bias = bm[k];
#pragma unroll
                for (int nt = 0; nt < 4; ++nt) {
                    const float t = accA[mt][nt][r] + bias;
                    ml[k][(wv << 6) + (nt << 4) + lm] = f2bf(1.0f / (1.0f + __expf(-t)));
                }
            }
        }
    __syncthreads();

    // ---- phase B: K = 256 px, 8 steps of 32 ----
    f32x4 acc2[2][8];
#pragma unroll
    for (int i = 0; i < 8; ++i) { acc2[0][i] = zz; acc2[1][i] = zz; }

    const float* xp = xb + p0;
    for (int ks = 0; ks < 8; ++ks) {
        const int pb = (ks << 5) + (q << 3);
        bf16x8 a0 = *(const bf16x8*)&ml[lm][pb];
        bf16x8 a1 = *(const bf16x8*)&ml[m1][pb];
#pragma unroll
        for (int cnt = 0; cnt < 8; ++cnt) {
            const int c = (wv << 7) + (cnt << 4) + lm;
            const float* src = xp + (size_t)c * HWHW + pb;
            float4 f0 = *(const float4*)(src);
            float4 f1 = *(const float4*)(src + 4);
            bf16x8 bv = { f2bf(f0.x), f2bf(f0.y), f2bf(f0.z), f2bf(f0.w),
                          f2bf(f1.x), f2bf(f1.y), f2bf(f1.z), f2bf(f1.w) };
            acc2[0][cnt] = __builtin_amdgcn_mfma_f32_16x16x32_bf16(a0, bv, acc2[0][cnt], 0, 0, 0);
            acc2[1][cnt] = __builtin_amdgcn_mfma_f32_16x16x32_bf16(a1, bv, acc2[1][cnt], 0, 0, 0);
        }
    }

    float* dst = cf_part + ((size_t)((s << 3) + b) * KK) * CC;
#pragma unroll
    for (int mt = 0; mt < 2; ++mt)
#pragma unroll
        for (int r = 0; r < 4; ++r) {
            const int k = (mt << 4) + (q << 2) + r;
            if (k < KK) {
#pragma unroll
                for (int cnt = 0; cnt < 8; ++cnt) {
                    const int c = (wv << 7) + (cnt << 4) + lm;
                    dst[(size_t)k * CC + c] = acc2[mt][cnt][r];
                }
            }
        }
}

// ========== k_s2r: cf = INV_HW * sum_s cf_part ==========
__global__ __launch_bounds__(256) void k_s2r(const float* __restrict__ part,
                                             float* __restrict__ cf) {
    const int i = blockIdx.x * 256 + threadIdx.x;
    if (i >= BB * KK * CC) return;
    const int b = i / (KK * CC);
    const int rem = i - b * (KK * CC);
    float sum = 0.0f;
#pragma unroll
    for (int s = 0; s < 64; ++s)
        sum += part[((size_t)((s << 3) + b) * KK) * CC + rem];
    cf[i] = sum * INV_HW;
}

// ====== k_filters: fil[b,k,o] = sum_c Wf[k,o,c]*cf[b,k,c] + bf[k,o] ======
__global__ __launch_bounds__(256) void k_filters(const float* __restrict__ Wf,
                                                 const float* __restrict__ bf,
                                                 const float* __restrict__ cf,
                                                 float* __restrict__ fil) {
    const int blk = blockIdx.x;
    const int k = blk >> 7;
    const int o = ((blk & 127) << 2) + (threadIdx.x >> 6);
    const int lane = threadIdx.x & 63;
    const float* wrow = Wf + ((size_t)k * CC + o) * CC;

    float acc[BB];
#pragma unroll
    for (int b = 0; b < BB; ++b) acc[b] = 0.0f;
#pragma unroll
    for (int j = 0; j < CC / 64; ++j) {
        const int c = lane + (j << 6);
        const float wv = wrow[c];
#pragma unroll
        for (int b = 0; b < BB; ++b)
            acc[b] += wv * cf[((size_t)b * KK + k) * CC + c];
    }
#pragma unroll
    for (int b = 0; b < BB; ++b) {
#pragma unroll
        for (int off = 32; off > 0; off >>= 1)
            acc[b] += __shfl_down(acc[b], off, 64);
    }
    if (lane == 0) {
        const float bias = bf[k * CC + o];
#pragma unroll
        for (int b = 0; b < BB; ++b)
            fil[((size_t)b * KK + k) * CC + o] = acc[b] + bias;
    }
}

// ============ k_s4: pred = fil[b] @ x, fp32 out. Same direct-global B ======
__global__ __launch_bounds__(256) void k_s4(const float* __restrict__ x,
                                            const float* __restrict__ fil,
                                            float* __restrict__ out) {
    __shared__ short wm[20][520];
    const int tid = threadIdx.x;
    const int b = blockIdx.x >> 6;
    const int p0 = (blockIdx.x & 63) << 8;
    const float* xb = x + (size_t)b * CC * HWHW;
    const float* fb = fil + (size_t)b * KK * CC;

    for (int u = tid; u < 20 * 128; u += 256) {
        const int k = u >> 7;
        const int c4 = (u & 127) << 2;
        float4 w = {0.f, 0.f, 0.f, 0.f};
        if (k < KK) w = *(const float4*)(fb + k * CC + c4);
        s16x4 v = { f2bf(w.x), f2bf(w.y), f2bf(w.z), f2bf(w.w) };
        *(s16x4*)&wm[k][c4] = v;
    }
    __syncthreads();

    const int wv = tid >> 6, ln = tid & 63;
    const int lm = ln & 15, q = ln >> 4;
    const int m1 = (lm < 3) ? (16 + lm) : 19;
    const int pw = p0 + (wv << 6);

    const f32x4 zz = {0.f, 0.f, 0.f, 0.f};
    f32x4 acc[2][4];
#pragma unroll
    for (int i = 0; i < 4; ++i) { acc[0][i] = zz; acc[1][i] = zz; }

    for (int cs = 0; cs < 16; ++cs) {
        const int cbase = (cs << 5) + (q << 3);
        bf16x8 a0 = *(const bf16x8*)&wm[lm][cbase];
        bf16x8 a1 = *(const bf16x8*)&wm[m1][cbase];
        const float* col = xb + (size_t)cbase * HWHW;
#pragma unroll
        for (int nt = 0; nt < 4; ++nt) {
            const int p = pw + (nt << 4) + lm;
            bf16x8 bv;
#pragma unroll
            for (int j = 0; j < 8; ++j)
                bv[j] = f2bf(col[(size_t)j * HWHW + p]);
            acc[0][nt] = __builtin_amdgcn_mfma_f32_16x16x32_bf16(a0, bv, acc[0][nt], 0, 0, 0);
            acc[1][nt] = __builtin_amdgcn_mfma_f32_16x16x32_bf16(a1, bv, acc[1][nt], 0, 0, 0);
        }
    }

    float* ob = out + (size_t)b * KK * HWHW;
#pragma unroll
    for (int mt = 0; mt < 2; ++mt)
#pragma unroll
        for (int r = 0; r < 4; ++r) {
            const int k = (mt << 4) + (q << 2) + r;
            if (k < KK) {
#pragma unroll
                for (int nt = 0; nt < 4; ++nt) {
                    const int p = pw + (nt << 4) + lm;
                    ob[(size_t)k * HWHW + p] = acc[mt][nt][r];
                }
            }
        }
}

extern "C" void kernel_launch(void* const* d_in, const int* in_sizes, int n_in,
                              void* d_out, int out_size, void* d_ws, size_t ws_size,
                              hipStream_t stream) {
    const float* x  = (const float*)d_in[0];
    const float* Wm = (const float*)d_in[1];
    const float* bm = (const float*)d_in[2];
    const float* Wf = (const float*)d_in[3];
    const float* bf = (const float*)d_in[4];
    float* out = (float*)d_out;

    float* cf_part = (float*)d_ws;                       // 64*8*19*512*4 = 24.9 MB
    float* cf  = cf_part + (size_t)64 * BB * KK * CC;    // 311 KB
    float* fil = cf + (size_t)BB * KK * CC;              // 311 KB

    k_s12<<<512, 256, 0, stream>>>(x, Wm, bm, cf_part);
    k_s2r<<<(BB * KK * CC + 255) / 256, 256, 0, stream>>>(cf_part, cf);
    k_filters<<<KK * 128, 256, 0, stream>>>(Wf, bf, cf, fil);
    k_s4<<<512, 256, 0, stream>>>(x, fil, out);
}